// Round 1
// baseline (359.057 us; speedup 1.0000x reference)
//
#include <hip/hip_runtime.h>

#define NB     4096
#define L_UID  200
#define L_ITEM 50
#define D_UID  64
#define D_ITEM 128
#define D_OUT  192

__global__ __launch_bounds__(256) void emb_pool_kernel(
    const int*   __restrict__ ids_uid,
    const int*   __restrict__ ids_item,
    const float* __restrict__ table_uid,
    const float* __restrict__ table_item,
    float*       __restrict__ out)
{
    const int b   = blockIdx.x;
    const int tid = threadIdx.x;

    __shared__ int   s_uid[L_UID];
    __shared__ int   s_item[L_ITEM];
    __shared__ float lds_uid[4][D_UID];    // per-wave partial sums
    __shared__ float lds_item[4][D_ITEM];
    __shared__ float lds_cnt[4];

    // Stage this row's ids into LDS (one global read each).
    if (tid < L_UID)  s_uid[tid]  = ids_uid [(size_t)b * L_UID  + tid];
    if (tid < L_ITEM) s_item[tid] = ids_item[(size_t)b * L_ITEM + tid];
    __syncthreads();

    const int wave = tid >> 6;
    const int lane = tid & 63;

    // ---------- uid: sum pool, D=64. 16 groups x 16 lanes; one float4/lane
    // covers a full 256 B table row per group-iteration. ----------
    {
        const int g = tid >> 4;   // 0..15
        const int l = tid & 15;   // 0..15
        float4 acc = make_float4(0.f, 0.f, 0.f, 0.f);
        for (int i = g; i < L_UID; i += 16) {
            const int   id = s_uid[i];
            const float m  = (id != 0) ? 1.0f : 0.0f;   // PADDING_IDX = 0
            const float4 v = *(const float4*)(table_uid + (size_t)id * D_UID + l * 4);
            acc.x += v.x * m; acc.y += v.y * m; acc.z += v.z * m; acc.w += v.w * m;
        }
        // Reduce 4 groups within the wave: xor 16, then xor 32.
        for (int off = 16; off < 64; off <<= 1) {
            acc.x += __shfl_xor(acc.x, off);
            acc.y += __shfl_xor(acc.y, off);
            acc.z += __shfl_xor(acc.z, off);
            acc.w += __shfl_xor(acc.w, off);
        }
        if (lane < 16)
            *(float4*)(&lds_uid[wave][lane * 4]) = acc;
    }

    // ---------- item: mean pool, D=128. 8 groups x 32 lanes; one float4/lane
    // covers a full 512 B table row per group-iteration. ----------
    {
        const int g = tid >> 5;   // 0..7
        const int l = tid & 31;   // 0..31
        float4 acc = make_float4(0.f, 0.f, 0.f, 0.f);
        float  cnt = 0.f;         // identical across all lanes of a group
        for (int i = g; i < L_ITEM; i += 8) {
            const int   id = s_item[i];
            const float m  = (id != 0) ? 1.0f : 0.0f;
            cnt += m;
            const float4 v = *(const float4*)(table_item + (size_t)id * D_ITEM + l * 4);
            acc.x += v.x * m; acc.y += v.y * m; acc.z += v.z * m; acc.w += v.w * m;
        }
        // Reduce the wave's 2 groups: xor 32 (also merges the counts).
        acc.x += __shfl_xor(acc.x, 32);
        acc.y += __shfl_xor(acc.y, 32);
        acc.z += __shfl_xor(acc.z, 32);
        acc.w += __shfl_xor(acc.w, 32);
        cnt   += __shfl_xor(cnt,   32);
        if (lane < 32) {
            *(float4*)(&lds_item[wave][lane * 4]) = acc;
            if (lane == 0) lds_cnt[wave] = cnt;
        }
    }
    __syncthreads();

    // ---------- cross-wave reduce + write ----------
    if (tid < 16) {   // uid: 16 lanes x float4 = 64 floats
        float4 a = *(const float4*)(&lds_uid[0][tid * 4]);
        #pragma unroll
        for (int w = 1; w < 4; ++w) {
            const float4 p = *(const float4*)(&lds_uid[w][tid * 4]);
            a.x += p.x; a.y += p.y; a.z += p.z; a.w += p.w;
        }
        *(float4*)(out + (size_t)b * D_OUT + tid * 4) = a;
    }
    if (tid >= 64 && tid < 96) {   // item: 32 lanes x float4 = 128 floats
        const int l = tid - 64;
        float4 a = *(const float4*)(&lds_item[0][l * 4]);
        #pragma unroll
        for (int w = 1; w < 4; ++w) {
            const float4 p = *(const float4*)(&lds_item[w][l * 4]);
            a.x += p.x; a.y += p.y; a.z += p.z; a.w += p.w;
        }
        const float c   = lds_cnt[0] + lds_cnt[1] + lds_cnt[2] + lds_cnt[3];
        const float inv = 1.0f / fmaxf(c, 1.0f);   // jnp.clip(denom, 1.0)
        a.x *= inv; a.y *= inv; a.z *= inv; a.w *= inv;
        *(float4*)(out + (size_t)b * D_OUT + D_UID + l * 4) = a;
    }
}

extern "C" void kernel_launch(void* const* d_in, const int* in_sizes, int n_in,
                              void* d_out, int out_size, void* d_ws, size_t ws_size,
                              hipStream_t stream) {
    const int*   ids_uid    = (const int*)  d_in[0];
    const int*   ids_item   = (const int*)  d_in[1];
    const float* table_uid  = (const float*)d_in[2];
    const float* table_item = (const float*)d_in[3];
    float*       out        = (float*)      d_out;

    emb_pool_kernel<<<NB, 256, 0, stream>>>(ids_uid, ids_item, table_uid, table_item, out);
}

// Round 2
// 358.484 us; speedup vs baseline: 1.0016x; 1.0016x over previous
//
#include <hip/hip_runtime.h>

#define NB          4096
#define L_UID       200
#define L_ITEM      50
#define L_UID_PAD   208   // 16 groups x 13 iters
#define L_ITEM_PAD  56    // 8 groups x 7 iters
#define IT_UID      13
#define IT_ITEM     7
#define D_UID       64
#define D_ITEM      128
#define D_OUT       192

__global__ __launch_bounds__(256) void emb_pool_kernel(
    const int*   __restrict__ ids_uid,
    const int*   __restrict__ ids_item,
    const float* __restrict__ table_uid,
    const float* __restrict__ table_item,
    float*       __restrict__ out)
{
    const int b   = blockIdx.x;
    const int tid = threadIdx.x;

    __shared__ int   s_uid[L_UID_PAD];
    __shared__ int   s_item[L_ITEM_PAD];
    __shared__ float lds_uid[4][D_UID];    // per-wave partial sums
    __shared__ float lds_item[4][D_ITEM];
    __shared__ float lds_cnt[4];

    // Stage ids into LDS; pad tail with 0 (PADDING_IDX) so loops are uniform.
    if (tid < L_UID)                      s_uid[tid]  = ids_uid [(size_t)b * L_UID  + tid];
    if (tid >= L_UID && tid < L_UID_PAD)  s_uid[tid]  = 0;
    if (tid < L_ITEM)                     s_item[tid] = ids_item[(size_t)b * L_ITEM + tid];
    if (tid >= L_ITEM && tid < L_ITEM_PAD) s_item[tid] = 0;
    __syncthreads();

    const int wave = tid >> 6;
    const int lane = tid & 63;

    // ---------- uid: sum pool, D=64. 16 groups x 16 lanes; one float4/lane
    // covers a full 256 B table row per group-iteration. Three-phase batched
    // form keeps all 13 gathers in flight per wave (MLP). ----------
    {
        const int g = tid >> 4;   // 0..15
        const int l = tid & 15;   // 0..15

        int   idv[IT_UID];
        float msk[IT_UID];
        #pragma unroll
        for (int it = 0; it < IT_UID; ++it) {
            idv[it] = s_uid[it * 16 + g];
            msk[it] = (idv[it] != 0) ? 1.0f : 0.0f;   // pad rows -> 0
        }

        float4 v[IT_UID];
        #pragma unroll
        for (int it = 0; it < IT_UID; ++it)
            v[it] = *(const float4*)(table_uid + (size_t)idv[it] * D_UID + l * 4);

        float4 acc = make_float4(0.f, 0.f, 0.f, 0.f);
        #pragma unroll
        for (int it = 0; it < IT_UID; ++it) {
            acc.x += v[it].x * msk[it];
            acc.y += v[it].y * msk[it];
            acc.z += v[it].z * msk[it];
            acc.w += v[it].w * msk[it];
        }

        // Reduce the wave's 4 groups: xor 16, then xor 32.
        for (int off = 16; off < 64; off <<= 1) {
            acc.x += __shfl_xor(acc.x, off);
            acc.y += __shfl_xor(acc.y, off);
            acc.z += __shfl_xor(acc.z, off);
            acc.w += __shfl_xor(acc.w, off);
        }
        if (lane < 16)
            *(float4*)(&lds_uid[wave][lane * 4]) = acc;
    }

    // ---------- item: mean pool, D=128. 8 groups x 32 lanes; one float4/lane
    // covers a full 512 B table row per group-iteration. ----------
    {
        const int g = tid >> 5;   // 0..7
        const int l = tid & 31;   // 0..31

        int   idv[IT_ITEM];
        float msk[IT_ITEM];
        #pragma unroll
        for (int it = 0; it < IT_ITEM; ++it) {
            idv[it] = s_item[it * 8 + g];
            msk[it] = (idv[it] != 0) ? 1.0f : 0.0f;
        }

        float4 v[IT_ITEM];
        #pragma unroll
        for (int it = 0; it < IT_ITEM; ++it)
            v[it] = *(const float4*)(table_item + (size_t)idv[it] * D_ITEM + l * 4);

        float4 acc = make_float4(0.f, 0.f, 0.f, 0.f);
        float  cnt = 0.f;         // identical across the group's 32 lanes
        #pragma unroll
        for (int it = 0; it < IT_ITEM; ++it) {
            cnt   += msk[it];
            acc.x += v[it].x * msk[it];
            acc.y += v[it].y * msk[it];
            acc.z += v[it].z * msk[it];
            acc.w += v[it].w * msk[it];
        }

        // Reduce the wave's 2 groups: xor 32 (also merges counts).
        acc.x += __shfl_xor(acc.x, 32);
        acc.y += __shfl_xor(acc.y, 32);
        acc.z += __shfl_xor(acc.z, 32);
        acc.w += __shfl_xor(acc.w, 32);
        cnt   += __shfl_xor(cnt,   32);
        if (lane < 32) {
            *(float4*)(&lds_item[wave][lane * 4]) = acc;
            if (lane == 0) lds_cnt[wave] = cnt;
        }
    }
    __syncthreads();

    // ---------- cross-wave reduce + write ----------
    if (tid < 16) {   // uid: 16 lanes x float4 = 64 floats
        float4 a = *(const float4*)(&lds_uid[0][tid * 4]);
        #pragma unroll
        for (int w = 1; w < 4; ++w) {
            const float4 p = *(const float4*)(&lds_uid[w][tid * 4]);
            a.x += p.x; a.y += p.y; a.z += p.z; a.w += p.w;
        }
        *(float4*)(out + (size_t)b * D_OUT + tid * 4) = a;
    }
    if (tid >= 64 && tid < 96) {   // item: 32 lanes x float4 = 128 floats
        const int l = tid - 64;
        float4 a = *(const float4*)(&lds_item[0][l * 4]);
        #pragma unroll
        for (int w = 1; w < 4; ++w) {
            const float4 p = *(const float4*)(&lds_item[w][l * 4]);
            a.x += p.x; a.y += p.y; a.z += p.z; a.w += p.w;
        }
        const float c   = lds_cnt[0] + lds_cnt[1] + lds_cnt[2] + lds_cnt[3];
        const float inv = 1.0f / fmaxf(c, 1.0f);   // jnp.clip(denom, 1.0)
        a.x *= inv; a.y *= inv; a.z *= inv; a.w *= inv;
        *(float4*)(out + (size_t)b * D_OUT + D_UID + l * 4) = a;
    }
}

extern "C" void kernel_launch(void* const* d_in, const int* in_sizes, int n_in,
                              void* d_out, int out_size, void* d_ws, size_t ws_size,
                              hipStream_t stream) {
    const int*   ids_uid    = (const int*)  d_in[0];
    const int*   ids_item   = (const int*)  d_in[1];
    const float* table_uid  = (const float*)d_in[2];
    const float* table_item = (const float*)d_in[3];
    float*       out        = (float*)      d_out;

    emb_pool_kernel<<<NB, 256, 0, stream>>>(ids_uid, ids_item, table_uid, table_item, out);
}

// Round 3
// 357.788 us; speedup vs baseline: 1.0035x; 1.0019x over previous
//
#include <hip/hip_runtime.h>

#define NB          4096
#define L_UID       200
#define L_ITEM      50
#define L_UID_PAD   208   // 16 groups x 13 iters
#define L_ITEM_PAD  56    // 8 groups x 7 iters
#define IT_UID      13
#define IT_ITEM     7
#define D_UID       64
#define D_ITEM      128
#define D_OUT       192

__global__ __launch_bounds__(256) void emb_pool_kernel(
    const int*   __restrict__ ids_uid,
    const int*   __restrict__ ids_item,
    const float* __restrict__ table_uid,
    const float* __restrict__ table_item,
    float*       __restrict__ out)
{
    const int b   = blockIdx.x;
    const int tid = threadIdx.x;

    __shared__ int   s_uid[L_UID_PAD];
    __shared__ int   s_item[L_ITEM_PAD];
    __shared__ float lds_uid[4][D_UID];    // per-wave partial sums
    __shared__ float lds_item[4][D_ITEM];
    __shared__ float lds_cnt[4];

    // Stage ids into LDS; pad tail with 0 (PADDING_IDX) so loops are uniform.
    if (tid < L_UID)                       s_uid[tid]  = ids_uid [(size_t)b * L_UID  + tid];
    else if (tid < L_UID_PAD)              s_uid[tid]  = 0;
    if (tid < L_ITEM)                      s_item[tid] = ids_item[(size_t)b * L_ITEM + tid];
    else if (tid < L_ITEM_PAD)             s_item[tid] = 0;
    __syncthreads();

    const int wave = tid >> 6;
    const int lane = tid & 63;
    const int gu = tid >> 4, lu = tid & 15;   // uid: 16 groups x 16 lanes
    const int gi = tid >> 5, li = tid & 31;   // item: 8 groups x 32 lanes

    // 32-bit byte offsets against SGPR base (tables are 256 MB / 51 MB,
    // offsets fit in 31 bits) -> single-VALU addressing per load.
    const char* __restrict__ tu = (const char*)table_uid;
    const char* __restrict__ ti = (const char*)table_item;

    unsigned uoff[IT_UID];  float umsk[IT_UID];
    #pragma unroll
    for (int it = 0; it < IT_UID; ++it) {
        const int id = s_uid[it * 16 + gu];
        umsk[it] = (id != 0) ? 1.0f : 0.0f;          // PADDING_IDX = 0
        uoff[it] = (unsigned)id * 256u + (unsigned)lu * 16u;
    }
    unsigned ioff[IT_ITEM]; float imsk[IT_ITEM];
    #pragma unroll
    for (int it = 0; it < IT_ITEM; ++it) {
        const int id = s_item[it * 8 + gi];
        imsk[it] = (id != 0) ? 1.0f : 0.0f;
        ioff[it] = (unsigned)id * 512u + (unsigned)li * 16u;
    }

    // Issue ALL 20 gathers into one in-flight window: item loads remain
    // outstanding while the uid accumulate+reduce runs.
    float4 uv[IT_UID];
    #pragma unroll
    for (int it = 0; it < IT_UID; ++it)
        uv[it] = *(const float4*)(tu + uoff[it]);
    float4 iv[IT_ITEM];
    #pragma unroll
    for (int it = 0; it < IT_ITEM; ++it)
        iv[it] = *(const float4*)(ti + ioff[it]);

    // ---------- uid: sum pool ----------
    {
        float4 acc = make_float4(0.f, 0.f, 0.f, 0.f);
        #pragma unroll
        for (int it = 0; it < IT_UID; ++it) {
            acc.x += uv[it].x * umsk[it];
            acc.y += uv[it].y * umsk[it];
            acc.z += uv[it].z * umsk[it];
            acc.w += uv[it].w * umsk[it];
        }
        for (int off = 16; off < 64; off <<= 1) {
            acc.x += __shfl_xor(acc.x, off);
            acc.y += __shfl_xor(acc.y, off);
            acc.z += __shfl_xor(acc.z, off);
            acc.w += __shfl_xor(acc.w, off);
        }
        if (lane < 16)
            *(float4*)(&lds_uid[wave][lane * 4]) = acc;
    }

    // ---------- item: mean pool ----------
    {
        float4 acc = make_float4(0.f, 0.f, 0.f, 0.f);
        float  cnt = 0.f;   // identical across the group's 32 lanes
        #pragma unroll
        for (int it = 0; it < IT_ITEM; ++it) {
            cnt   += imsk[it];
            acc.x += iv[it].x * imsk[it];
            acc.y += iv[it].y * imsk[it];
            acc.z += iv[it].z * imsk[it];
            acc.w += iv[it].w * imsk[it];
        }
        acc.x += __shfl_xor(acc.x, 32);
        acc.y += __shfl_xor(acc.y, 32);
        acc.z += __shfl_xor(acc.z, 32);
        acc.w += __shfl_xor(acc.w, 32);
        cnt   += __shfl_xor(cnt,   32);
        if (lane < 32) {
            *(float4*)(&lds_item[wave][lane * 4]) = acc;
            if (lane == 0) lds_cnt[wave] = cnt;
        }
    }
    __syncthreads();

    // ---------- cross-wave reduce + write ----------
    if (tid < 16) {   // uid: 16 lanes x float4 = 64 floats
        float4 a = *(const float4*)(&lds_uid[0][tid * 4]);
        #pragma unroll
        for (int w = 1; w < 4; ++w) {
            const float4 p = *(const float4*)(&lds_uid[w][tid * 4]);
            a.x += p.x; a.y += p.y; a.z += p.z; a.w += p.w;
        }
        *(float4*)(out + (size_t)b * D_OUT + tid * 4) = a;
    }
    if (tid >= 64 && tid < 96) {   // item: 32 lanes x float4 = 128 floats
        const int l = tid - 64;
        float4 a = *(const float4*)(&lds_item[0][l * 4]);
        #pragma unroll
        for (int w = 1; w < 4; ++w) {
            const float4 p = *(const float4*)(&lds_item[w][l * 4]);
            a.x += p.x; a.y += p.y; a.z += p.z; a.w += p.w;
        }
        const float c   = lds_cnt[0] + lds_cnt[1] + lds_cnt[2] + lds_cnt[3];
        const float inv = 1.0f / fmaxf(c, 1.0f);   // jnp.clip(denom, 1.0)
        a.x *= inv; a.y *= inv; a.z *= inv; a.w *= inv;
        *(float4*)(out + (size_t)b * D_OUT + D_UID + l * 4) = a;
    }
}

extern "C" void kernel_launch(void* const* d_in, const int* in_sizes, int n_in,
                              void* d_out, int out_size, void* d_ws, size_t ws_size,
                              hipStream_t stream) {
    const int*   ids_uid    = (const int*)  d_in[0];
    const int*   ids_item   = (const int*)  d_in[1];
    const float* table_uid  = (const float*)d_in[2];
    const float* table_item = (const float*)d_in[3];
    float*       out        = (float*)      d_out;

    emb_pool_kernel<<<NB, 256, 0, stream>>>(ids_uid, ids_item, table_uid, table_item, out);
}